// Round 2
// baseline (113.413 us; speedup 1.0000x reference)
//
#include <hip/hip_runtime.h>

#define TLEN 8192
#define DD   4096
#define NF   10
#define NC   12   // 10 a_f coeffs + g + pad
#define NACC 12   // x_sum, pooled, h_f (f=0..9)

// ---------- helpers ----------
__device__ __forceinline__ double powi_d(double w, int n) {
    double a = 1.0, p = w;
    while (n) { if (n & 1) a *= p; p *= p; n >>= 1; }
    return a;
}

// ---------- kernel 1: per-timestep coefficient tables ----------
// coef[t*12 + f] = w_f^(T-1-t)            (weight of x_t in h_final[f])
// coef[t*12 +10] = g(t) = sum_f pw_f * (1 - w_f^(T-1-t)) / (1 - w_f)
__global__ void coef_kernel(const float* __restrict__ w,
                            const float* __restrict__ pool_w,
                            float* __restrict__ coef) {
    int t = blockIdx.x * blockDim.x + threadIdx.x;
    if (t >= TLEN) return;
    int n = TLEN - 1 - t;
    double g = 0.0;
#pragma unroll
    for (int f = 0; f < NF; ++f) {
        double wf = (double)w[(size_t)f * DD];     // broadcast along D
        double a  = powi_d(wf, n);
        double den = 1.0 - wf;
        double c  = (den > 1e-30) ? (1.0 - a) / den : (double)n;
        g += (double)pool_w[f] * c;
        coef[t * NC + f] = (float)a;
    }
    coef[t * NC + NF]     = (float)g;
    coef[t * NC + NF + 1] = 0.0f;
}

// ---------- kernel 2: single streaming pass over inp ----------
// Each block: 1024 d-columns (256 threads x float4), `rows` timesteps.
// Produces partials: part[(chunk*12 + acc)*DD + d],
//   acc 0 = x_sum, acc 1 = pooled_raw, acc 2+f = h_final[f].
__global__ __launch_bounds__(256) void pass_kernel(const float* __restrict__ inp,
                                                   const float* __restrict__ coef,
                                                   float* __restrict__ part,
                                                   int rows) {
    __shared__ float sc[256 * NC];  // staged coefficients, <=256 rows per refill
    const int t0 = blockIdx.y * rows;
    const int d  = blockIdx.x * 1024 + threadIdx.x * 4;

    float sx=0,sy=0,sz=0,sw=0;           // x_sum
    float px=0,py=0,pz=0,pw4=0;          // pooled_raw
    float hx[NF], hy[NF], hz[NF], hw[NF];
#pragma unroll
    for (int f = 0; f < NF; ++f) { hx[f]=0; hy[f]=0; hz[f]=0; hw[f]=0; }

    const float* ip = inp + (size_t)t0 * DD + d;

    for (int rbase = 0; rbase < rows; rbase += 256) {
        int rcnt = rows - rbase; if (rcnt > 256) rcnt = 256;
        __syncthreads();
        for (int i = threadIdx.x; i < rcnt * NC; i += 256)
            sc[i] = coef[(size_t)(t0 + rbase) * NC + i];
        __syncthreads();
        for (int r = 0; r < rcnt; ++r) {
            float4 x = *(const float4*)ip;
            ip += DD;
            const float* cf = &sc[r * NC];
            sx += x.x; sy += x.y; sz += x.z; sw += x.w;
            float g = cf[NF];
            px  = fmaf(g, x.x, px);  py  = fmaf(g, x.y, py);
            pz  = fmaf(g, x.z, pz);  pw4 = fmaf(g, x.w, pw4);
#pragma unroll
            for (int f = 0; f < NF; ++f) {
                float a = cf[f];
                hx[f] = fmaf(a, x.x, hx[f]); hy[f] = fmaf(a, x.y, hy[f]);
                hz[f] = fmaf(a, x.z, hz[f]); hw[f] = fmaf(a, x.w, hw[f]);
            }
        }
    }

    size_t base = ((size_t)blockIdx.y * NC) * DD + d;
    *(float4*)(part + base)      = make_float4(sx, sy, sz, sw);
    *(float4*)(part + base + DD) = make_float4(px, py, pz, pw4);
#pragma unroll
    for (int f = 0; f < NF; ++f)
        *(float4*)(part + base + (size_t)(2 + f) * DD) =
            make_float4(hx[f], hy[f], hz[f], hw[f]);
}

// ---------- kernel 3: reduce partials over chunks ----------
// one thread per (acc, d) scalar; acc in [0,12)  -- ALL 12 accumulators
__global__ void reduce_kernel(const float* __restrict__ part,
                              float* __restrict__ red, int C) {
    int idx = blockIdx.x * blockDim.x + threadIdx.x;  // 0 .. 12*4096
    if (idx >= NACC * DD) return;
    float s = 0.0f;
    for (int c = 0; c < C; ++c)
        s += part[(size_t)c * NC * DD + idx];
    red[idx] = s;
}

// ---------- kernel 4: finalize h_final + avg vector ----------
__global__ void finalize_kernel(const float* __restrict__ red,
                                const float* __restrict__ w,
                                const float* __restrict__ pool_w,
                                const float* __restrict__ pool_b,
                                const float* __restrict__ hidden,
                                float* __restrict__ out,
                                float* __restrict__ avg) {
    int i = blockIdx.x * blockDim.x + threadIdx.x;   // 0..1023
    int d = i * 4;
    float4 xs = *(const float4*)(red + d);
    float4 pl = *(const float4*)(red + DD + d);
    const float invT = 1.0f / (float)TLEN;
#pragma unroll
    for (int f = 0; f < NF; ++f) {
        double wf = (double)w[(size_t)f * DD];
        double wTd = powi_d(wf, TLEN);
        double den = 1.0 - wf;
        double sTd = (den > 1e-30) ? (1.0 - wTd) / den : (double)TLEN;
        float wT = (float)wTd;
        float pwsT = (float)((double)pool_w[f] * sTd);
        float4 hf = *(const float4*)(red + (size_t)(2 + f) * DD + d);
        float4 h0 = *(const float4*)(hidden + (size_t)f * DD + d);
        hf.x = fmaf(wT, h0.x, hf.x); hf.y = fmaf(wT, h0.y, hf.y);
        hf.z = fmaf(wT, h0.z, hf.z); hf.w = fmaf(wT, h0.w, hf.w);
        pl.x = fmaf(pwsT, h0.x, pl.x); pl.y = fmaf(pwsT, h0.y, pl.y);
        pl.z = fmaf(pwsT, h0.z, pl.z); pl.w = fmaf(pwsT, h0.w, pl.w);
        float* o = out + 10 + (size_t)f * DD + d;   // unaligned for float4 -> scalar
        o[0] = hf.x; o[1] = hf.y; o[2] = hf.z; o[3] = hf.w;
    }
    float pb = pool_b[0];
    avg[d+0] = xs.x * invT; avg[d+1] = xs.y * invT;
    avg[d+2] = xs.z * invT; avg[d+3] = xs.w * invT;
    avg[DD + d + 0] = pl.x * invT + pb; avg[DD + d + 1] = pl.y * invT + pb;
    avg[DD + d + 2] = pl.z * invT + pb; avg[DD + d + 3] = pl.w * invT + pb;
}

// ---------- kernel 5: GEMV  hid = relu(i2o_w @ avg + i2o_b) ----------
__global__ __launch_bounds__(256) void gemv_kernel(const float* __restrict__ W,
                                                   const float* __restrict__ b,
                                                   const float* __restrict__ avg,
                                                   float* __restrict__ hid) {
    int row  = blockIdx.x * 4 + (threadIdx.x >> 6);
    int lane = threadIdx.x & 63;
    const float* wr = W + (size_t)row * (2 * DD);
    float acc = 0.0f;
#pragma unroll 8
    for (int j0 = 0; j0 < 32; ++j0) {
        int j = j0 * 256 + lane * 4;
        float4 wv = *(const float4*)(wr + j);
        float4 av = *(const float4*)(avg + j);
        acc = fmaf(wv.x, av.x, acc); acc = fmaf(wv.y, av.y, acc);
        acc = fmaf(wv.z, av.z, acc); acc = fmaf(wv.w, av.w, acc);
    }
    for (int off = 32; off; off >>= 1) acc += __shfl_down(acc, off, 64);
    if (lane == 0) hid[row] = fmaxf(acc + b[row], 0.0f);
}

// ---------- kernel 6: final 10-way dot ----------
__global__ void out_kernel(const float* __restrict__ hid,
                           const float* __restrict__ ow,
                           const float* __restrict__ ob,
                           float* __restrict__ out) {
    __shared__ float redl[256];
    int o = blockIdx.x;
    float acc = 0.0f;
    for (int h = threadIdx.x; h < DD; h += 256)
        acc = fmaf(hid[h], ow[(size_t)o * DD + h], acc);
    redl[threadIdx.x] = acc;
    __syncthreads();
    for (int s = 128; s; s >>= 1) {
        if (threadIdx.x < s) redl[threadIdx.x] += redl[threadIdx.x + s];
        __syncthreads();
    }
    if (threadIdx.x == 0) out[o] = redl[0] + ob[o];
}

extern "C" void kernel_launch(void* const* d_in, const int* in_sizes, int n_in,
                              void* d_out, int out_size, void* d_ws, size_t ws_size,
                              hipStream_t stream) {
    const float* inp    = (const float*)d_in[0];
    const float* hidden = (const float*)d_in[1];
    const float* w      = (const float*)d_in[2];
    const float* pw     = (const float*)d_in[3];
    const float* pb     = (const float*)d_in[4];
    const float* i2o_w  = (const float*)d_in[5];
    const float* i2o_b  = (const float*)d_in[6];
    const float* o_w    = (const float*)d_in[7];
    const float* o_b    = (const float*)d_in[8];
    float* out = (float*)d_out;
    float* ws  = (float*)d_ws;

    // workspace layout (floats)
    float* coef = ws;                 // 8192*12           = 98304
    float* red  = ws + 98304;         // 12*4096           = 49152
    float* avg  = ws + 147456;        // 8192
    float* hid  = ws + 155648;        // 4096
    float* part = ws + 159744;        // C*12*4096

    // pick chunk count C fitting the workspace (prefer 128)
    int C = 128;
    while (C > 1) {
        size_t need = (159744 + (size_t)C * NC * DD) * sizeof(float);
        if (need <= ws_size) break;
        C >>= 1;
    }
    int rows = TLEN / C;

    coef_kernel<<<TLEN / 256, 256, 0, stream>>>(w, pw, coef);
    pass_kernel<<<dim3(4, C), 256, 0, stream>>>(inp, coef, part, rows);
    reduce_kernel<<<(NACC * DD + 255) / 256, 256, 0, stream>>>(part, red, C);
    finalize_kernel<<<4, 256, 0, stream>>>(red, w, pw, pb, hidden, out, avg);
    gemv_kernel<<<DD / 4, 256, 0, stream>>>(i2o_w, i2o_b, avg, hid);
    out_kernel<<<10, 256, 0, stream>>>(hid, o_w, o_b, out);
}